// Round 6
// baseline (495.942 us; speedup 1.0000x reference)
//
#include <hip/hip_runtime.h>
#include <cstdint>
#include <cstddef>

#define BB 16
#define CIN 512
#define NPIX 4096   // 64*64
#define C8 64
#define C2 256
#define MM 1024     // pooled positions 32*32

using bf16x8 = __attribute__((ext_vector_type(8))) short;
using f32x4  = __attribute__((ext_vector_type(4))) float;

__device__ __forceinline__ short f2bf(float f) {
  union { float f; unsigned u; } v; v.f = f;
  unsigned r = v.u + 0x7FFFu + ((v.u >> 16) & 1u);
  return (short)(r >> 16);
}
// packed f32x2 -> bf16x2 (RNE), single HW instr on gfx950
__device__ __forceinline__ unsigned cvtpk(float lo, float hi) {
  unsigned r;
  asm("v_cvt_pk_bf16_f32 %0, %1, %2" : "=v"(r) : "v"(lo), "v"(hi));
  return r;
}
__device__ __forceinline__ bf16x8 ldg8(const short* p) {
  return *reinterpret_cast<const bf16x8*>(p);
}
__device__ __forceinline__ bf16x8 lds8(const short* p) {  // 8B-aligned LDS read
  union { unsigned long long q[2]; bf16x8 v; } u;
  u.q[0] = *reinterpret_cast<const unsigned long long*>(p);
  u.q[1] = *reinterpret_cast<const unsigned long long*>(p + 4);
  return u.v;
}
__device__ __forceinline__ void sts8(short* p, bf16x8 v) {  // 8B-aligned LDS write
  union { unsigned long long q[2]; bf16x8 v; } u; u.v = v;
  *reinterpret_cast<unsigned long long*>(p) = u.q[0];
  *reinterpret_cast<unsigned long long*>(p + 4) = u.q[1];
}
#define MFMA(a, b, c) __builtin_amdgcn_mfma_f32_16x16x32_bf16(a, b, c, 0, 0, 0)
#define LOG2E 1.4426950408889634f

// ---------------------------------------------------------------------------
// weight casts: Wtheta(32768) | Wphi(32768) | Wg(131072) | Wo(131072) floats
// Wtheta pre-scaled by log2(e) so softmax can use raw exp2 (v_exp_f32).
// ---------------------------------------------------------------------------
__global__ __launch_bounds__(256) void cast_w_k(const float* __restrict__ wa,
                                                const float* __restrict__ wb,
                                                const float* __restrict__ wc,
                                                const float* __restrict__ wd,
                                                short* __restrict__ out) {
  int i = blockIdx.x * 256 + threadIdx.x;
  float v;
  if (i < 32768) v = wa[i] * LOG2E;
  else if (i < 65536) v = wb[i - 32768];
  else if (i < 196608) v = wc[i - 65536];
  else v = wd[i - 196608];
  out[i] = f2bf(v);
}

// ---------------------------------------------------------------------------
// conv_mega v6: 1024 threads (16 waves), 2-chunk-deep x register prefetch,
// raw lgkm-only barriers, setprio around MFMA. (unchanged this round)
// ---------------------------------------------------------------------------
__global__ __launch_bounds__(1024) void conv_mega_k(
    const float* __restrict__ x, const short* __restrict__ wbf,
    const float* __restrict__ bth, const float* __restrict__ bph,
    const float* __restrict__ bg,
    short* __restrict__ thetaT, short* __restrict__ phiT,
    short* __restrict__ gp) {
  __shared__ __align__(16) short xs[128][36];   // stride 72B: 8B-aligned rows
  const int t = threadIdx.x, w = t >> 6, l = t & 63;
  const int lr = l & 15, quad = l >> 4;
  const int wg = w & 7, wh = w >> 3;
  const int bx = blockIdx.x, b = blockIdx.y;
  const int nbase = bx * 128;
  const float* xb = x + ((size_t)b * CIN << 12) + nbase;

  const int nl = t & 127, cg = t >> 7;   // cg in 0..7

  f32x4 acc[3][4];
#pragma unroll
  for (int i = 0; i < 3; ++i)
#pragma unroll
    for (int j = 0; j < 4; ++j) acc[i][j] = (f32x4){0.f, 0.f, 0.f, 0.f};

  float pv0[2][2], pv1[2][2];
#pragma unroll
  for (int s = 0; s < 2; ++s)
#pragma unroll
    for (int p = 0; p < 2; ++p) {
      int cl = s * 32 + (p * 8 + cg) * 2;
      pv0[s][p] = xb[((size_t)cl << 12) + nl];
      pv1[s][p] = xb[((size_t)(cl + 1) << 12) + nl];
    }

  for (int c0 = 0; c0 < CIN; c0 += 32) {
    const int slot = (c0 >> 5) & 1;
    bf16x8 af[3];
#pragma unroll
    for (int tt = 0; tt < 3; ++tt)
      af[tt] = ldg8(wbf + (size_t)(wg * 48 + tt * 16 + lr) * CIN + c0 + quad * 8);
    asm volatile("s_waitcnt lgkmcnt(0)" ::: "memory");
    __builtin_amdgcn_s_barrier();   // prev chunk's LDS reads complete (WAR)
#pragma unroll
    for (int p = 0; p < 2; ++p) {
      int cl = (p * 8 + cg) * 2;
      *reinterpret_cast<unsigned*>(&xs[nl][cl]) = cvtpk(pv0[slot][p], pv1[slot][p]);
    }
    asm volatile("s_waitcnt lgkmcnt(0)" ::: "memory");
    __builtin_amdgcn_s_barrier();   // xs visible
    if (c0 + 64 < CIN) {
#pragma unroll
      for (int p = 0; p < 2; ++p) {
        int cl = (p * 8 + cg) * 2;
        pv0[slot][p] = xb[((size_t)(c0 + 64 + cl) << 12) + nl];
        pv1[slot][p] = xb[((size_t)(c0 + 64 + cl + 1) << 12) + nl];
      }
    }
    __builtin_amdgcn_s_setprio(1);
#pragma unroll
    for (int j = 0; j < 4; ++j) {
      const int gnt = (j & 1) + wh * 2 + (j >> 1) * 4;
      bf16x8 bfr = lds8(&xs[gnt * 16 + lr][quad * 8]);
#pragma unroll
      for (int tt = 0; tt < 3; ++tt)
        acc[tt][j] = MFMA(af[tt], bfr, acc[tt][j]);
    }
    __builtin_amdgcn_s_setprio(0);
  }

#pragma unroll
  for (int tt = 0; tt < 3; ++tt) {
    const int ocb = wg * 48 + tt * 16;
    if (ocb < 64) {           // theta: no pool, (n, 64) layout, scaled by log2e
      short* tb = thetaT + ((size_t)b << 12) * C8;
#pragma unroll
      for (int r = 0; r < 4; ++r) {
        int oc = ocb + quad * 4 + r;
        float bia = bth[oc] * LOG2E;
#pragma unroll
        for (int j = 0; j < 4; ++j) {
          const int gnt = (j & 1) + wh * 2 + (j >> 1) * 4;
          int n = nbase + gnt * 16 + lr;
          tb[(size_t)n * C8 + oc] = f2bf(fmaxf(acc[tt][j][r] + bia, 0.f));
        }
      }
    } else if (ocb < 128) {   // phi: pool, (m, 64) layout
      short* pb = phiT + ((size_t)b << 10) * C8;
#pragma unroll
      for (int r = 0; r < 4; ++r) {
        int oc = ocb - 64 + quad * 4 + r;
        float bia = bph[oc];
#pragma unroll
        for (int jj = 0; jj < 2; ++jj) {
          float va = fmaxf(acc[tt][jj][r] + bia, 0.f);      // image row 0
          float vb = fmaxf(acc[tt][jj + 2][r] + bia, 0.f);  // image row 1
          float pa = fmaxf(va, __shfl_xor(va, 1));
          float pbv = fmaxf(vb, __shfl_xor(vb, 1));
          float pool = fmaxf(pa, pbv);
          if ((l & 1) == 0) {
            int m = bx * 32 + wh * 16 + jj * 8 + (lr >> 1);
            pb[(size_t)m * C8 + oc] = f2bf(pool);
          }
        }
      }
    } else {                  // g: pool, (256, 1024) c-major layout
      short* gb = gp + ((size_t)b << 10) * C2;
#pragma unroll
      for (int r = 0; r < 4; ++r) {
        int oc = ocb - 128 + quad * 4 + r;
        float bia = bg[oc];
#pragma unroll
        for (int jj = 0; jj < 2; ++jj) {
          float va = fmaxf(acc[tt][jj][r] + bia, 0.f);
          float vb = fmaxf(acc[tt][jj + 2][r] + bia, 0.f);
          float pa = fmaxf(va, __shfl_xor(va, 1));
          float pbv = fmaxf(vb, __shfl_xor(vb, 1));
          float pool = fmaxf(pa, pbv);
          if ((l & 1) == 0) {
            int m = bx * 32 + wh * 16 + jj * 8 + (lr >> 1);
            gb[(size_t)oc * MM + m] = f2bf(pool);
          }
        }
      }
    }
  }
}

// ---------------------------------------------------------------------------
// attn_k v7: occupancy doubling. Block = 32 queries, 4 waves, <=128 unified
// regs/wave (launch_bounds(256,4)) -> 4 waves/SIMD (was 2 at ~180 regs).
// Scores split (qh = w&1: q group of 16; mh = w>>1: m half of 64): sacc[4]
// (16 regs, was 32); per-q max combined across the wave pair via LDS cm +
// one extra barrier (both waves compute identical mnew/alpha -> defer-max
// stays deterministic). PV: wave w covers c [64w,+64) x 32 q -> oacc[4][2]
// = 32 AGPR (was 64); ga 4-frag kc-rotate (was 16-frag / 64 VGPR).
// LDS ~35KB -> 4 blocks/CU resident. Grid 2048 (same XCD swizzle, 2 b/XCD).
// ---------------------------------------------------------------------------
__global__ __launch_bounds__(256, 4) void attn_k(
    const short* __restrict__ thetaT, const short* __restrict__ phiT,
    const short* __restrict__ gp, const short* __restrict__ wo,
    const float* __restrict__ bo, const float* __restrict__ x,
    const float* __restrict__ gamma, float* __restrict__ out) {
  // smem: ps[2][32][132] (8448 shorts) unioned with os[32][264] (8448 shorts)
  __shared__ __align__(16) short smem[8448];
  __shared__ __align__(16) short phs[128][68];   // phi chunk 128m x 64c, pad->68
  __shared__ float cm[4][16];          // per-wave cmax exchange
  __shared__ float balpha[2][2][16];   // [buf][qh][lr]
  __shared__ float bsum[4][16];
  __shared__ float binv[2][16];
  const int t = threadIdx.x, w = t >> 6, l = t & 63;
  const int lr = l & 15, quad = l >> 4;
  const int qh = w & 1, mh = w >> 1;
  const int blk = blockIdx.x;
  const int b = ((blk & 7) << 1) | ((blk >> 3) & 1);   // 2 batches per XCD
  const int q0 = (blk >> 4) << 5;                       // 32 q per block

  const short* thb = thetaT + ((size_t)b << 12) * C8;
  const short* phb = phiT + ((size_t)b << 10) * C8;
  const short* gpb = gp + ((size_t)b << 10) * C2;

  // theta B-frags for this wave's 16 queries (n = q0 + qh*16 + lr)
  bf16x8 tb0 = ldg8(thb + (size_t)(q0 + qh * 16 + lr) * C8 + quad * 8);
  bf16x8 tb1 = ldg8(thb + (size_t)(q0 + qh * 16 + lr) * C8 + 32 + quad * 8);

  f32x4 oacc[4][2];   // [ct][qt]: c = 64w+16ct+quad*4+r, n = q0+16qt+lr
#pragma unroll
  for (int i = 0; i < 4; ++i)
#pragma unroll
    for (int j = 0; j < 2; ++j) oacc[i][j] = (f32x4){0.f, 0.f, 0.f, 0.f};
  float mrun = -3e38f, ssum = 0.f;

  // cooperative phi staging: thread t covers rows sw*32 + (t>>3), col (t&7)*8
  const int srow = t >> 3, scol = (t & 7) * 8;
  bf16x8 stld[4];
  auto stage_phi_issue = [&](int ch) {
    const int m0 = ch * 128;
#pragma unroll
    for (int sw = 0; sw < 4; ++sw)
      stld[sw] = ldg8(phb + (size_t)(m0 + sw * 32 + srow) * C8 + scol);
  };
  auto stage_phi_write = [&]() {
#pragma unroll
    for (int sw = 0; sw < 4; ++sw)
      sts8(&phs[sw * 32 + srow][scol], stld[sw]);
  };

  // scores+softmax for chunk ch: wave computes S[64m (mh half) x 16q (qh)]
  auto scores = [&](int ch) {
    const int buf = ch & 1;
    f32x4 sacc[4];
#pragma unroll
    for (int i = 0; i < 4; ++i) sacc[i] = (f32x4){0.f, 0.f, 0.f, 0.f};
    __builtin_amdgcn_s_setprio(1);
#pragma unroll
    for (int mt = 0; mt < 4; ++mt) {
      const short* pr = &phs[mh * 64 + mt * 16 + lr][quad * 8];
      sacc[mt] = MFMA(lds8(pr), tb0, sacc[mt]);
      sacc[mt] = MFMA(lds8(pr + 32), tb1, sacc[mt]);
    }
    __builtin_amdgcn_s_setprio(0);
    float cmax = sacc[0][0];
#pragma unroll
    for (int mt = 0; mt < 4; ++mt)
      cmax = fmaxf(cmax, fmaxf(fmaxf(sacc[mt][0], sacc[mt][1]),
                               fmaxf(sacc[mt][2], sacc[mt][3])));
    cmax = fmaxf(cmax, __shfl_xor(cmax, 16));
    cmax = fmaxf(cmax, __shfl_xor(cmax, 32));
    if (quad == 0) cm[w][lr] = cmax;
    asm volatile("s_waitcnt lgkmcnt(0)" ::: "memory");
    __builtin_amdgcn_s_barrier();        // cm ready
    const float cboth = fmaxf(cmax, cm[w ^ 2][lr]);
    // defer-max: keep mrun unless max grew >8 (P bounded by 2^8, f32-safe);
    // both waves of the pair compute identical mnew/alpha (deterministic)
    const float mnew = (cboth > mrun + 8.f) ? cboth : mrun;
    const float al = exp2f(mrun - mnew);   // == 1.0f when deferred
    mrun = mnew;
    float rsum = 0.f;
    short* prow = smem + ((buf * 32 + qh * 16 + lr) * 132) + mh * 64;
#pragma unroll
    for (int mt = 0; mt < 4; ++mt) {
      float e0 = exp2f(sacc[mt][0] - mnew);
      float e1 = exp2f(sacc[mt][1] - mnew);
      float e2 = exp2f(sacc[mt][2] - mnew);
      float e3 = exp2f(sacc[mt][3] - mnew);
      rsum += (e0 + e1) + (e2 + e3);
      uint2 pk2;
      pk2.x = cvtpk(e0, e1);
      pk2.y = cvtpk(e2, e3);
      *reinterpret_cast<uint2*>(prow + mt * 16 + quad * 4) = pk2;
    }
    ssum = ssum * al + rsum;
    if (quad == 0 && mh == 0) balpha[buf][qh][lr] = al;
  };

  // kc0 ga prefetch (4 frags), issued at scores-tail, spans b1
  bf16x8 gpf[4];
  auto pfga = [&](int ch) {
    const int m0 = ch * 128;
#pragma unroll
    for (int ct = 0; ct < 4; ++ct)
      gpf[ct] = ldg8(gpb + (size_t)(w * 64 + ct * 16 + lr) * MM + m0 + quad * 8);
  };

  // prologue
  stage_phi_issue(0);
  stage_phi_write();
  asm volatile("s_waitcnt lgkmcnt(0)" ::: "memory");
  __builtin_amdgcn_s_barrier();   // phi(0) visible
  scores(0);
  pfga(0);

  for (int ch = 0; ch < 8; ++ch) {
    const int buf = ch & 1, m0 = ch * 128;
    asm volatile("s_waitcnt lgkmcnt(0)" ::: "memory");
    __builtin_amdgcn_s_barrier();   // b1: ps[buf]+balpha ready; phs free
    if (ch < 7) stage_phi_issue(ch + 1);   // global loads fly over PV
    float av0 = balpha[buf][0][lr], av1 = balpha[buf][1][lr];
    if (av0 != 1.f || av1 != 1.f) {
#pragma unroll
      for (int ct = 0; ct < 4; ++ct) {
        oacc[ct][0] *= av0;
        oacc[ct][1] *= av1;
      }
    }
    // PV: wave w covers c [64w, +64), 32 queries; ga rotated one kc ahead
    __builtin_amdgcn_s_setprio(1);
    bf16x8 cga[4];
#pragma unroll
    for (int ct = 0; ct < 4; ++ct) cga[ct] = gpf[ct];
#pragma unroll
    for (int kc = 0; kc < 4; ++kc) {
      bf16x8 nga[4];
      if (kc < 3) {
#pragma unroll
        for (int ct = 0; ct < 4; ++ct)
          nga[ct] = ldg8(gpb + (size_t)(w * 64 + ct * 16 + lr) * MM +
                         m0 + (kc + 1) * 32 + quad * 8);
      }
      bf16x8 pf[2];
#pragma unroll
      for (int qt = 0; qt < 2; ++qt)
        pf[qt] = lds8(smem + ((buf * 32 + qt * 16 + lr) * 132) +
                      kc * 32 + quad * 8);
#pragma unroll
      for (int ct = 0; ct < 4; ++ct)
#pragma unroll
        for (int qt = 0; qt < 2; ++qt)
          oacc[ct][qt] = MFMA(cga[ct], pf[qt], oacc[ct][qt]);
      if (kc < 3) {
#pragma unroll
        for (int i = 0; i < 4; ++i) cga[i] = nga[i];
      }
    }
    __builtin_amdgcn_s_setprio(0);
    if (ch < 7) {
      stage_phi_write();              // waits phi loads, writes phs
      asm volatile("s_waitcnt lgkmcnt(0)" ::: "memory");
      __builtin_amdgcn_s_barrier();   // b2: phi(ch+1) visible
      scores(ch + 1);                 // reads phs, writes ps[!buf]
      pfga(ch + 1);                   // spans next b1
    }
  }

  // ---- final softmax denominators: sum quads, then wave-pair halves ----
  ssum += __shfl_xor(ssum, 16);
  ssum += __shfl_xor(ssum, 32);
  if (quad == 0) bsum[w][lr] = ssum;
  __syncthreads();   // all PV done (smem reusable as os), bsum ready
  if (quad == 0 && mh == 0) binv[qh][lr] = 1.f / (bsum[w][lr] + bsum[w ^ 2][lr]);
  __syncthreads();   // binv ready
  float invn[2] = {binv[0][lr], binv[1][lr]};

  // ---- write o to LDS as (32 n x 264 c-padded), rows n-local = 16qt+lr ----
  short (*os)[264] = reinterpret_cast<short (*)[264]>(smem);
#pragma unroll
  for (int ct = 0; ct < 4; ++ct) {
    int c0 = w * 64 + ct * 16 + quad * 4;
#pragma unroll
    for (int qt = 0; qt < 2; ++qt) {
      uint2 pk2;
      pk2.x = cvtpk(oacc[ct][qt][0] * invn[qt], oacc[ct][qt][1] * invn[qt]);
      pk2.y = cvtpk(oacc[ct][qt][2] * invn[qt], oacc[ct][qt][3] * invn[qt]);
      *reinterpret_cast<uint2*>(&os[qt * 16 + lr][c0]) = pk2;
    }
  }
  __syncthreads();   // os complete

  // ---- fused final conv: wave w -> oc [128w,+128) in 4 passes of 32 ----
  const float g0 = gamma[0];
  for (int pp = 0; pp < 4; ++pp) {
    const int ocb = w * 128 + pp * 32;
    f32x4 acc2[2][2];
#pragma unroll
    for (int i = 0; i < 2; ++i)
#pragma unroll
      for (int j = 0; j < 2; ++j) acc2[i][j] = (f32x4){0.f, 0.f, 0.f, 0.f};
#pragma unroll
    for (int half = 0; half < 2; ++half) {
      // batch 8 wa loads (4 kc x 2 ot) for this half
      bf16x8 wa[8];
#pragma unroll
      for (int k2 = 0; k2 < 4; ++k2)
#pragma unroll
        for (int ot = 0; ot < 2; ++ot)
          wa[k2 * 2 + ot] = ldg8(wo + (size_t)(ocb + ot * 16 + lr) * C2 +
                                 (half * 4 + k2) * 32 + quad * 8);
      __builtin_amdgcn_s_setprio(1);
#pragma unroll
      for (int k2 = 0; k2 < 4; ++k2) {
        const int kc = half * 4 + k2;
        bf16x8 of[2];
#pragma unroll
        for (int qt = 0; qt < 2; ++qt)
          of[qt] = lds8(&os[qt * 16 + lr][kc * 32 + quad * 8]);
#pragma unroll
        for (int ot = 0; ot < 2; ++ot)
#pragma unroll
          for (int qt = 0; qt < 2; ++qt)
            acc2[ot][qt] = MFMA(wa[k2 * 2 + ot], of[qt], acc2[ot][qt]);
      }
      __builtin_amdgcn_s_setprio(0);
    }
#pragma unroll
    for (int ot = 0; ot < 2; ++ot) {
#pragma unroll
      for (int r = 0; r < 4; ++r) {
        int oc = ocb + ot * 16 + quad * 4 + r;
        float bia = bo[oc];
        size_t base = ((size_t)(b * CIN + oc) << 12);
#pragma unroll
        for (int qt = 0; qt < 2; ++qt) {
          int n = q0 + qt * 16 + lr;
          float v = g0 * fmaxf(acc2[ot][qt][r] + bia, 0.f);
          out[base + n] = v + x[base + n];
        }
      }
    }
  }
}

// ---------------------------------------------------------------------------
extern "C" void kernel_launch(void* const* d_in, const int* in_sizes, int n_in,
                              void* d_out, int out_size, void* d_ws, size_t ws_size,
                              hipStream_t stream) {
  const float* x       = (const float*)d_in[0];
  const float* W_theta = (const float*)d_in[1];
  const float* b_theta = (const float*)d_in[2];
  const float* W_phi   = (const float*)d_in[3];
  const float* b_phi   = (const float*)d_in[4];
  const float* W_g     = (const float*)d_in[5];
  const float* b_g     = (const float*)d_in[6];
  const float* W_o     = (const float*)d_in[7];
  const float* b_o     = (const float*)d_in[8];
  const float* gamma   = (const float*)d_in[9];
  float* out = (float*)d_out;
  char* W = (char*)d_ws;

  // workspace (bytes): thetaT 8,388,608 | phiT 2,097,152 | gp 8,388,608 | wbf 655,360
  short* thetaT = (short*)(W);
  short* phiT   = (short*)(W + 8388608);
  short* gp     = (short*)(W + 10485760);
  short* wbf    = (short*)(W + 18874368);
  short* wo     = wbf + 196608;

  cast_w_k<<<dim3(1280), 256, 0, stream>>>(W_theta, W_phi, W_g, W_o, wbf);
  conv_mega_k<<<dim3(32, 16), 1024, 0, stream>>>(x, wbf, b_theta, b_phi, b_g,
                                                 thetaT, phiT, gp);
  attn_k<<<dim3(2048), 256, 0, stream>>>(thetaT, phiT, gp, wo, b_o, x, gamma, out);
}

// Round 7
// 393.245 us; speedup vs baseline: 1.2612x; 1.2612x over previous
//
#include <hip/hip_runtime.h>
#include <cstdint>
#include <cstddef>

#define BB 16
#define CIN 512
#define NPIX 4096   // 64*64
#define C8 64
#define C2 256
#define MM 1024     // pooled positions 32*32

using bf16x8 = __attribute__((ext_vector_type(8))) short;
using f32x4  = __attribute__((ext_vector_type(4))) float;

__device__ __forceinline__ short f2bf(float f) {
  union { float f; unsigned u; } v; v.f = f;
  unsigned r = v.u + 0x7FFFu + ((v.u >> 16) & 1u);
  return (short)(r >> 16);
}
// packed f32x2 -> bf16x2 (RNE), single HW instr on gfx950
__device__ __forceinline__ unsigned cvtpk(float lo, float hi) {
  unsigned r;
  asm("v_cvt_pk_bf16_f32 %0, %1, %2" : "=v"(r) : "v"(lo), "v"(hi));
  return r;
}
__device__ __forceinline__ bf16x8 ldg8(const short* p) {
  return *reinterpret_cast<const bf16x8*>(p);
}
__device__ __forceinline__ bf16x8 lds8(const short* p) {  // 8B-aligned LDS read
  union { unsigned long long q[2]; bf16x8 v; } u;
  u.q[0] = *reinterpret_cast<const unsigned long long*>(p);
  u.q[1] = *reinterpret_cast<const unsigned long long*>(p + 4);
  return u.v;
}
__device__ __forceinline__ void sts8(short* p, bf16x8 v) {  // 8B-aligned LDS write
  union { unsigned long long q[2]; bf16x8 v; } u; u.v = v;
  *reinterpret_cast<unsigned long long*>(p) = u.q[0];
  *reinterpret_cast<unsigned long long*>(p + 4) = u.q[1];
}
#define MFMA(a, b, c) __builtin_amdgcn_mfma_f32_16x16x32_bf16(a, b, c, 0, 0, 0)
#define LOG2E 1.4426950408889634f

// ---------------------------------------------------------------------------
// weight casts: Wtheta(32768) | Wphi(32768) | Wg(131072) | Wo(131072) floats
// Wtheta pre-scaled by log2(e) so softmax can use raw exp2 (v_exp_f32).
// ---------------------------------------------------------------------------
__global__ __launch_bounds__(256) void cast_w_k(const float* __restrict__ wa,
                                                const float* __restrict__ wb,
                                                const float* __restrict__ wc,
                                                const float* __restrict__ wd,
                                                short* __restrict__ out) {
  int i = blockIdx.x * 256 + threadIdx.x;
  float v;
  if (i < 32768) v = wa[i] * LOG2E;
  else if (i < 65536) v = wb[i - 32768];
  else if (i < 196608) v = wc[i - 65536];
  else v = wd[i - 196608];
  out[i] = f2bf(v);
}

// ---------------------------------------------------------------------------
// conv_mega v8: back to the 512-thread / 24-MFMA-per-wave structure (v5's
// 1024-thread split regressed ~50us: half the MFMA work per barrier, 16-wave
// barriers), plus:
//  - xs double-buffered -> ONE barrier per chunk (was 2). Stage-writes of
//    chunk i+1 go to xs[buf^1] while compute reads xs[buf]; the end-of-iter
//    barrier gives writes a full chunk of slack.
//  - 2-deep x register prefetch (chunk i+3 issued at iter i) so ~900cy HBM
//    latency spans two chunk periods.
//  - setprio around the MFMA cluster.
// Loop fully unrolled: pv slot arrays must be statically indexed (else
// scratch).
// ---------------------------------------------------------------------------
__global__ __launch_bounds__(512) void conv_mega_k(
    const float* __restrict__ x, const short* __restrict__ wbf,
    const float* __restrict__ bth, const float* __restrict__ bph,
    const float* __restrict__ bg,
    short* __restrict__ thetaT, short* __restrict__ phiT,
    short* __restrict__ gp) {
  __shared__ __align__(16) short xs[2][128][36];   // 2 x 9KB, stride 72B rows
  const int t = threadIdx.x, w = t >> 6, l = t & 63;
  const int lr = l & 15, quad = l >> 4;
  const int bx = blockIdx.x, b = blockIdx.y;
  const int nbase = bx * 128;
  const float* xb = x + ((size_t)b * CIN << 12) + nbase;

  // staging mapping: nl = t&127 (pixel), cp = t>>7 (0..3); p: cl = (p*4+cp)*2
  const int nl = t & 127, cp = t >> 7;

  f32x4 acc[3][8];
#pragma unroll
  for (int i = 0; i < 3; ++i)
#pragma unroll
    for (int j = 0; j < 8; ++j) acc[i][j] = (f32x4){0.f, 0.f, 0.f, 0.f};

  float pv0[2][4], pv1[2][4];
  // prologue: issue chunks 0 and 1
#pragma unroll
  for (int s = 0; s < 2; ++s)
#pragma unroll
    for (int p = 0; p < 4; ++p) {
      int cl = s * 32 + (p * 4 + cp) * 2;
      pv0[s][p] = xb[((size_t)cl << 12) + nl];
      pv1[s][p] = xb[((size_t)(cl + 1) << 12) + nl];
    }
  // write chunk 0 into xs[0]
#pragma unroll
  for (int p = 0; p < 4; ++p) {
    int cl = (p * 4 + cp) * 2;
    *reinterpret_cast<unsigned*>(&xs[0][nl][cl]) = cvtpk(pv0[0][p], pv1[0][p]);
  }
  // reload slot 0 with chunk 2
#pragma unroll
  for (int p = 0; p < 4; ++p) {
    int cl = 64 + (p * 4 + cp) * 2;
    pv0[0][p] = xb[((size_t)cl << 12) + nl];
    pv1[0][p] = xb[((size_t)(cl + 1) << 12) + nl];
  }
  asm volatile("s_waitcnt lgkmcnt(0)" ::: "memory");
  __builtin_amdgcn_s_barrier();   // xs[0] visible

#pragma unroll
  for (int i = 0; i < 16; ++i) {
    const int c0 = i * 32, buf = i & 1;
    bf16x8 af[3];
#pragma unroll
    for (int tt = 0; tt < 3; ++tt)
      af[tt] = ldg8(wbf + (size_t)(w * 48 + tt * 16 + lr) * CIN + c0 + quad * 8);
    if (i < 15) {
      // stage chunk i+1 from slot buf^1 into xs[buf^1] (no reader this iter)
#pragma unroll
      for (int p = 0; p < 4; ++p) {
        int cl = (p * 4 + cp) * 2;
        *reinterpret_cast<unsigned*>(&xs[buf ^ 1][nl][cl]) =
            cvtpk(pv0[buf ^ 1][p], pv1[buf ^ 1][p]);
      }
      if (i < 13) {
        // refill slot buf^1 with chunk i+3 (in flight for 2 chunk periods)
#pragma unroll
        for (int p = 0; p < 4; ++p) {
          int cl = (i + 3) * 32 + (p * 4 + cp) * 2;
          pv0[buf ^ 1][p] = xb[((size_t)cl << 12) + nl];
          pv1[buf ^ 1][p] = xb[((size_t)(cl + 1) << 12) + nl];
        }
      }
    }
    __builtin_amdgcn_s_setprio(1);
#pragma unroll
    for (int nt = 0; nt < 8; ++nt) {
      bf16x8 bfr = lds8(&xs[buf][nt * 16 + lr][quad * 8]);
#pragma unroll
      for (int tt = 0; tt < 3; ++tt)
        acc[tt][nt] = MFMA(af[tt], bfr, acc[tt][nt]);
    }
    __builtin_amdgcn_s_setprio(0);
    asm volatile("s_waitcnt lgkmcnt(0)" ::: "memory");
    __builtin_amdgcn_s_barrier();   // writes(i+1) visible; reads(i) done (WAR)
  }

#pragma unroll
  for (int tt = 0; tt < 3; ++tt) {
    const int ocb = w * 48 + tt * 16;
    if (ocb < 64) {           // theta: no pool, (n, 64) layout, scaled by log2e
      short* tb = thetaT + ((size_t)b << 12) * C8;
#pragma unroll
      for (int r = 0; r < 4; ++r) {
        int oc = ocb + quad * 4 + r;
        float bia = bth[oc] * LOG2E;
#pragma unroll
        for (int nt = 0; nt < 8; ++nt) {
          int n = nbase + nt * 16 + lr;
          tb[(size_t)n * C8 + oc] = f2bf(fmaxf(acc[tt][nt][r] + bia, 0.f));
        }
      }
    } else if (ocb < 128) {   // phi: pool, (m, 64) layout
      short* pb = phiT + ((size_t)b << 10) * C8;
#pragma unroll
      for (int r = 0; r < 4; ++r) {
        int oc = ocb - 64 + quad * 4 + r;
        float bia = bph[oc];
#pragma unroll
        for (int nt = 0; nt < 4; ++nt) {
          float va = fmaxf(acc[tt][nt][r] + bia, 0.f);
          float vb = fmaxf(acc[tt][nt + 4][r] + bia, 0.f);
          float pa = fmaxf(va, __shfl_xor(va, 1));
          float pbv = fmaxf(vb, __shfl_xor(vb, 1));
          float pool = fmaxf(pa, pbv);
          if ((l & 1) == 0) {
            int m = bx * 32 + nt * 8 + (lr >> 1);
            pb[(size_t)m * C8 + oc] = f2bf(pool);
          }
        }
      }
    } else {                  // g: pool, (256, 1024) c-major layout
      short* gb = gp + ((size_t)b << 10) * C2;
#pragma unroll
      for (int r = 0; r < 4; ++r) {
        int oc = ocb - 128 + quad * 4 + r;
        float bia = bg[oc];
#pragma unroll
        for (int nt = 0; nt < 4; ++nt) {
          float va = fmaxf(acc[tt][nt][r] + bia, 0.f);
          float vb = fmaxf(acc[tt][nt + 4][r] + bia, 0.f);
          float pa = fmaxf(va, __shfl_xor(va, 1));
          float pbv = fmaxf(vb, __shfl_xor(vb, 1));
          float pool = fmaxf(pa, pbv);
          if ((l & 1) == 0) {
            int m = bx * 32 + nt * 8 + (lr >> 1);
            gb[(size_t)oc * MM + m] = f2bf(pool);
          }
        }
      }
    }
  }
}

// ---------------------------------------------------------------------------
// attn_k v6 (round-5 version, restored verbatim: 152us proven): 64 q / block,
// 4 waves; phi staged once per block into LDS; full-chunk ga prefetch
// gpf[16] issued pre-barrier; defer-max (THR=8, exp2 domain); setprio around
// MFMA clusters; 2 raw lgkm-only barriers per chunk.
// ---------------------------------------------------------------------------
__global__ __launch_bounds__(256, 2) void attn_k(
    const short* __restrict__ thetaT, const short* __restrict__ phiT,
    const short* __restrict__ gp, const short* __restrict__ wo,
    const float* __restrict__ bo, const float* __restrict__ x,
    const float* __restrict__ gamma, float* __restrict__ out) {
  // ps[2][4][16][132] (33792 shorts) unioned with os[64][264]
  __shared__ __align__(16) short smem[16896];
  __shared__ __align__(16) short phs[128][68];   // phi chunk 128m x 64c, pad->68
  __shared__ float balpha[2][4][16];
  __shared__ float binv[4][16];
  const int t = threadIdx.x, w = t >> 6, l = t & 63;
  const int lr = l & 15, quad = l >> 4;
  const int blk = blockIdx.x;
  const int b = ((blk & 7) << 1) | ((blk >> 3) & 1);   // 2 batches per XCD
  const int q0 = (blk >> 4) << 6;
  const int nw = q0 + w * 16;

  const short* thb = thetaT + ((size_t)b << 12) * C8;
  const short* phb = phiT + ((size_t)b << 10) * C8;
  const short* gpb = gp + ((size_t)b << 10) * C2;

  bf16x8 tb0 = ldg8(thb + (size_t)(nw + lr) * C8 + quad * 8);
  bf16x8 tb1 = ldg8(thb + (size_t)(nw + lr) * C8 + 32 + quad * 8);

  f32x4 oacc[4][4];   // [ct][qt]: c = 64w+16ct+quad*4+r, n = q0+16qt+lr
#pragma unroll
  for (int i = 0; i < 4; ++i)
#pragma unroll
    for (int j = 0; j < 4; ++j) oacc[i][j] = (f32x4){0.f, 0.f, 0.f, 0.f};
  float mrun = -3e38f, ssum = 0.f;

  // cooperative phi staging: thread t covers rows sw*32 + (t>>3), col (t&7)*8
  const int srow = t >> 3, scol = (t & 7) * 8;
  bf16x8 stld[4];
  auto stage_phi_issue = [&](int ch) {
    const int m0 = ch * 128;
#pragma unroll
    for (int sw = 0; sw < 4; ++sw)
      stld[sw] = ldg8(phb + (size_t)(m0 + sw * 32 + srow) * C8 + scol);
  };
  auto stage_phi_write = [&]() {
#pragma unroll
    for (int sw = 0; sw < 4; ++sw)
      sts8(&phs[sw * 32 + srow][scol], stld[sw]);
  };

  // scores+softmax for chunk ch (phi from LDS) -> ps[ch&1], balpha[ch&1]
  auto scores = [&](int ch) {
    const int buf = ch & 1;
    f32x4 sacc[8];
#pragma unroll
    for (int i = 0; i < 8; ++i) sacc[i] = (f32x4){0.f, 0.f, 0.f, 0.f};
    __builtin_amdgcn_s_setprio(1);
#pragma unroll
    for (int mt = 0; mt < 8; ++mt) {
      const short* pr = &phs[mt * 16 + lr][quad * 8];
      sacc[mt] = MFMA(lds8(pr), tb0, sacc[mt]);
      sacc[mt] = MFMA(lds8(pr + 32), tb1, sacc[mt]);
    }
    __builtin_amdgcn_s_setprio(0);
    float cmax = sacc[0][0];
#pragma unroll
    for (int mt = 0; mt < 8; ++mt)
      cmax = fmaxf(cmax, fmaxf(fmaxf(sacc[mt][0], sacc[mt][1]),
                               fmaxf(sacc[mt][2], sacc[mt][3])));
    cmax = fmaxf(cmax, __shfl_xor(cmax, 16));
    cmax = fmaxf(cmax, __shfl_xor(cmax, 32));
    // defer-max: keep mrun unless max grew >8 (P bounded by 2^8, f32-safe)
    const float mnew = (cmax > mrun + 8.f) ? cmax : mrun;
    const float al = exp2f(mrun - mnew);   // == 1.0f when deferred
    mrun = mnew;
    float rsum = 0.f;
    short* prow = smem + ((((buf << 2) | w) << 4) + lr) * 132;
#pragma unroll
    for (int mt = 0; mt < 8; ++mt) {
      float e0 = exp2f(sacc[mt][0] - mnew);
      float e1 = exp2f(sacc[mt][1] - mnew);
      float e2 = exp2f(sacc[mt][2] - mnew);
      float e3 = exp2f(sacc[mt][3] - mnew);
      rsum += (e0 + e1) + (e2 + e3);
      uint2 pk2;
      pk2.x = cvtpk(e0, e1);
      pk2.y = cvtpk(e2, e3);
      *reinterpret_cast<uint2*>(prow + mt * 16 + quad * 4) = pk2;
    }
    ssum = ssum * al + rsum;
    if (quad == 0) balpha[buf][w][lr] = al;
  };

  // full-chunk ga prefetch (16 frags, issued pre-barrier, spans b1)
  bf16x8 gpf[16];
  auto pfga = [&](int ch) {
    const int m0 = ch * 128;
#pragma unroll
    for (int kc = 0; kc < 4; ++kc)
#pragma unroll
      for (int ct = 0; ct < 4; ++ct)
        gpf[kc * 4 + ct] = ldg8(gpb + (size_t)(w * 64 + ct * 16 + lr) * MM +
                                m0 + kc * 32 + quad * 8);
  };

  // prologue: stage phi(0), scores(0), prefetch ga(0)
  stage_phi_issue(0);
  stage_phi_write();
  asm volatile("s_waitcnt lgkmcnt(0)" ::: "memory");
  __builtin_amdgcn_s_barrier();   // phi(0) visible
  scores(0);
  pfga(0);

  for (int ch = 0; ch < 8; ++ch) {
    const int buf = ch & 1;
    asm volatile("s_waitcnt lgkmcnt(0)" ::: "memory");
    __builtin_amdgcn_s_barrier();   // b1: ps[buf]+balpha ready; phs free
    if (ch < 7) stage_phi_issue(ch + 1);   // global loads fly over PV
    float av[4];
#pragma unroll
    for (int qt = 0; qt < 4; ++qt) av[qt] = balpha[buf][qt][lr];
    if (av[0] != 1.f || av[1] != 1.f || av[2] != 1.f || av[3] != 1.f) {
#pragma unroll
      for (int ct = 0; ct < 4; ++ct)
#pragma unroll
        for (int qt = 0; qt < 4; ++qt) oacc[ct][qt] *= av[qt];
    }
    // PV: wave w covers c [64w, 64w+64), all 64 queries, ga pre-fetched
    __builtin_amdgcn_s_setprio(1);
#pragma unroll
    for (int kc = 0; kc < 4; ++kc) {
      bf16x8 pf[4];
#pragma unroll
      for (int qt = 0; qt < 4; ++qt)
        pf[qt] = lds8(smem + ((((buf << 2) | qt) << 4) + lr) * 132 +
                      kc * 32 + quad * 8);
#pragma unroll
      for (int ct = 0; ct < 4; ++ct)
#pragma unroll
        for (int qt = 0; qt < 4; ++qt)
          oacc[ct][qt] = MFMA(gpf[kc * 4 + ct], pf[qt], oacc[ct][qt]);
    }
    __builtin_amdgcn_s_setprio(0);
    if (ch < 7) {
      stage_phi_write();              // waits its 4 loads, writes phs
      asm volatile("s_waitcnt lgkmcnt(0)" ::: "memory");
      __builtin_amdgcn_s_barrier();   // b2: phi(ch+1) visible
      scores(ch + 1);                 // reads phs, writes ps[!buf]
      pfga(ch + 1);                   // spans next b1
    }
  }

  // ---- final softmax denominators ----
  ssum += __shfl_xor(ssum, 16);
  ssum += __shfl_xor(ssum, 32);
  if (quad == 0) binv[w][lr] = 1.f / ssum;
  __syncthreads();   // all PV/scores done (smem reusable as os), binv ready
  float invn[4];
#pragma unroll
  for (int qt = 0; qt < 4; ++qt) invn[qt] = binv[qt][lr];

  // ---- write o to LDS as (64 n x 256 c), rows n-local = 16qt+lr ----
  short (*os)[264] = reinterpret_cast<short (*)[264]>(smem);
#pragma unroll
  for (int ct = 0; ct < 4; ++ct) {
    int c0 = w * 64 + ct * 16 + quad * 4;
#pragma unroll
    for (int qt = 0; qt < 4; ++qt) {
      uint2 pk2;
      pk2.x = cvtpk(oacc[ct][qt][0] * invn[qt], oacc[ct][qt][1] * invn[qt]);
      pk2.y = cvtpk(oacc[ct][qt][2] * invn[qt], oacc[ct][qt][3] * invn[qt]);
      *reinterpret_cast<uint2*>(&os[qt * 16 + lr][c0]) = pk2;
    }
  }
  __syncthreads();   // os complete

  // ---- fused final conv: wave w -> oc [128w,+128) in 4 passes of 32 ----
  const float g0 = gamma[0];
  for (int pp = 0; pp < 4; ++pp) {
    const int ocb = w * 128 + pp * 32;
    f32x4 acc2[2][4];
#pragma unroll
    for (int i = 0; i < 2; ++i)
#pragma unroll
      for (int j = 0; j < 4; ++j) acc2[i][j] = (f32x4){0.f, 0.f, 0.f, 0.f};
#pragma unroll
    for (int half = 0; half < 2; ++half) {
      // batch 8 wa loads (4 kc x 2 ot) for this half
      bf16x8 wa[8];
#pragma unroll
      for (int k2 = 0; k2 < 4; ++k2)
#pragma unroll
        for (int ot = 0; ot < 2; ++ot)
          wa[k2 * 2 + ot] = ldg8(wo + (size_t)(ocb + ot * 16 + lr) * C2 +
                                 (half * 4 + k2) * 32 + quad * 8);
      __builtin_amdgcn_s_setprio(1);
#pragma unroll
      for (int k2 = 0; k2 < 4; ++k2) {
        const int kc = half * 4 + k2;
        bf16x8 of[4];
#pragma unroll
        for (int qt = 0; qt < 4; ++qt)
          of[qt] = lds8(&os[qt * 16 + lr][kc * 32 + quad * 8]);
#pragma unroll
        for (int ot = 0; ot < 2; ++ot)
#pragma unroll
          for (int qt = 0; qt < 4; ++qt)
            acc2[ot][qt] = MFMA(wa[k2 * 2 + ot], of[qt], acc2[ot][qt]);
      }
      __builtin_amdgcn_s_setprio(0);
    }
#pragma unroll
    for (int ot = 0; ot < 2; ++ot) {
#pragma unroll
      for (int r = 0; r < 4; ++r) {
        int oc = ocb + ot * 16 + quad * 4 + r;
        float bia = bo[oc];
        size_t base = ((size_t)(b * CIN + oc) << 12);
#pragma unroll
        for (int qt = 0; qt < 4; ++qt) {
          int n = q0 + qt * 16 + lr;
          float v = g0 * fmaxf(acc2[ot][qt][r] + bia, 0.f);
          out[base + n] = v + x[base + n];
        }
      }
    }
  }
}

// ---------------------------------------------------------------------------
extern "C" void kernel_launch(void* const* d_in, const int* in_sizes, int n_in,
                              void* d_out, int out_size, void* d_ws, size_t ws_size,
                              hipStream_t stream) {
  const float* x       = (const float*)d_in[0];
  const float* W_theta = (const float*)d_in[1];
  const float* b_theta = (const float*)d_in[2];
  const float* W_phi   = (const float*)d_in[3];
  const float* b_phi   = (const float*)d_in[4];
  const float* W_g     = (const float*)d_in[5];
  const float* b_g     = (const float*)d_in[6];
  const float* W_o     = (const float*)d_in[7];
  const float* b_o     = (const float*)d_in[8];
  const float* gamma   = (const float*)d_in[9];
  float* out = (float*)d_out;
  char* W = (char*)d_ws;

  // workspace (bytes): thetaT 8,388,608 | phiT 2,097,152 | gp 8,388,608 | wbf 655,360
  short* thetaT = (short*)(W);
  short* phiT   = (short*)(W + 8388608);
  short* gp     = (short*)(W + 10485760);
  short* wbf    = (short*)(W + 18874368);
  short* wo     = wbf + 196608;

  cast_w_k<<<dim3(1280), 256, 0, stream>>>(W_theta, W_phi, W_g, W_o, wbf);
  conv_mega_k<<<dim3(32, 16), 512, 0, stream>>>(x, wbf, b_theta, b_phi, b_g,
                                                thetaT, phiT, gp);
  attn_k<<<dim3(1024), 256, 0, stream>>>(thetaT, phiT, gp, wo, b_o, x, gamma, out);
}